// Round 14
// baseline (137.908 us; speedup 1.0000x reference)
//
#include <hip/hip_runtime.h>
#include <cmath>

#define Bsz 4
#define Ssz 2048
#define Dsz 512
#define Hn 8

typedef unsigned short u16;
typedef _Float16 f16;
typedef __attribute__((ext_vector_type(4))) _Float16 f16x4;
typedef __attribute__((ext_vector_type(8))) _Float16 f16x8;
typedef __attribute__((ext_vector_type(8))) unsigned short us8;
typedef __attribute__((ext_vector_type(4))) float f32x4;
typedef __attribute__((ext_vector_type(16))) float f32x16;

__device__ __forceinline__ void gl2lds16(const void* g, void* l) {
    __builtin_amdgcn_global_load_lds(
        (const __attribute__((address_space(1))) void*)g,
        (__attribute__((address_space(3))) void*)l, 16, 0, 0);
}

// ---- fused prep: blocks [0,2048) convert x (fp32->fp16, 8/thread);
//      blocks [2048,2304) transpose+convert the 4 weight matrices;
//      block 2304 builds the attn schedule map (anti-correlated pairing).
__global__ __launch_bounds__(256) void prep(const float* __restrict__ x,
                                            f16* __restrict__ xb,
                                            const float* __restrict__ Wq,
                                            const float* __restrict__ Wk,
                                            const float* __restrict__ Wv,
                                            const float* __restrict__ Wo,
                                            f16* __restrict__ Wtqkv,
                                            f16* __restrict__ Wto,
                                            const int* __restrict__ gids,
                                            int* __restrict__ smap) {
    const int blk = blockIdx.x;
    const int tid = threadIdx.x;
    if (blk == 2304) {                     // schedule-map builder
        __shared__ int cntS[64];
        __shared__ int rnk[64];
        if (tid < 64) {
            int b = tid >> 4, qt = tid & 15;
            const int* Gb = gids + b * Ssz;
            int gqmin = Gb[qt * 128], gqmax = Gb[qt * 128 + 127];
            int c = 0;
            for (int kt = 0; kt < 32; kt++) {
                int gf = Gb[kt * 64], gl = Gb[kt * 64 + 63];
                c += (gl >= gqmin && gf <= gqmax) ? 1 : 0;
            }
            cntS[tid] = c;
        }
        __syncthreads();
        if (tid < 64) {
            int c = cntS[tid], r = 0;
            for (int j = 0; j < 64; j++) {
                int cj = cntS[j];
                r += ((cj > c) || (cj == c && j < tid)) ? 1 : 0;
            }
            rnk[tid] = r;
        }
        __syncthreads();
        if (tid < 64) {
            int r = rnk[tid];
            int b = tid >> 4, qt = tid & 15;
            int enc = qt | (b << 7);
#pragma unroll
            for (int h = 0; h < 8; h++) {
                int inst = r * 8 + h;
                int slot = (inst < 256) ? inst : 767 - inst;
                smap[slot] = enc | (h << 4);
            }
        }
        return;
    }
    if (blk < 2048) {
        int i = blk * 256 + tid;
        const float4* xv = (const float4*)x;
        float4 a = xv[2 * i], b = xv[2 * i + 1];
        f16x8 o;
        o[0] = (f16)a.x; o[1] = (f16)a.y; o[2] = (f16)a.z; o[3] = (f16)a.w;
        o[4] = (f16)b.x; o[5] = (f16)b.y; o[6] = (f16)b.z; o[7] = (f16)b.w;
        ((f16x8*)xb)[i] = o;
        return;
    }
    __shared__ float T[64][65];
    const int bz = blk - 2048;             // 256 blocks: 8 x 8 x 4
    const int z = bz >> 6;
    const int n0 = (bz & 7) * 64, k0 = ((bz >> 3) & 7) * 64;
    const float* W = (z == 0) ? Wq : (z == 1) ? Wk : (z == 2) ? Wv : Wo;
#pragma unroll
    for (int i = 0; i < 16; i++) {
        int e = tid + i * 256;
        int r = e >> 6, c = e & 63;
        T[r][c] = W[(size_t)(k0 + r) * Dsz + n0 + c];
    }
    __syncthreads();
    f16* dst = (z < 3) ? (Wtqkv + ((size_t)z * 512 + n0) * Dsz + k0)
                       : (Wto + (size_t)n0 * Dsz + k0);
#pragma unroll
    for (int i = 0; i < 16; i++) {
        int e = tid + i * 256;
        int r = e >> 6, c = e & 63;
        dst[(size_t)r * Dsz + c] = (f16)(T[c][r]);
    }
}

// ---- 128x128-tile fp16 MFMA GEMM (32x32x16), C = relu(A @ Bt^T + bias) ----
// R11: counted-vmcnt double-buffer (T3/T4). R12: XCD-slab swizzle (T1).
// R13: BK template param (gemm0 BK=32 -> 32KB LDS, all 768 blocks resident).
// R14: setprio(1/0) around MFMA cluster (T5; role-split schedule). Also a
// determinism probe: setprio cannot change values/FP-order, so absmax must
// stay EXACTLY 0.0234375 if R13 is deterministic; any shift => BK=32 staging
// races => revert BK=64 next round.
// MODE 0: Q (x0.125) / K row-major f16; V -> packed V^T tiles. MODE 1: fp32.
template <int MODE, int NCOL, int BK>
__global__ __launch_bounds__(256) void gemm128(
    const f16* __restrict__ A, const f16* __restrict__ Bt,
    f16* o0, f16* o1, u16* o2v,
    const float* b0, const float* b1, const float* b2,
    float* ofp, const float* bias_f) {
    constexpr int CPR = BK / 8;            // 16B chunks per row
    constexpr int NT = 512 / BK;           // K-tiles
    constexpr int BUFE = 2 * 128 * BK;     // u16 elements per buffer (A+B)
    __shared__ __align__(16) u16 smem[2 * BUFE];
    const int tid = threadIdx.x;
    // XCD-slab swizzle: bid%8 = XCD (round-robin dispatch assumption)
    const int bid = blockIdx.x;
    const int xcd = bid & 7;
    const int idx = bid >> 3;
    const int colg0 = (idx % NCOL) * 128;
    const int row0 = (xcd * 8 + idx / NCOL) * 128;
    const int w = tid >> 6, lane = tid & 63;
    const int nn = lane & 31, hh = lane >> 5;
    const int wr = w >> 1, wc = w & 1;

    f32x16 acc[2][2];
#pragma unroll
    for (int bi = 0; bi < 2; bi++)
#pragma unroll
        for (int bj = 0; bj < 2; bj++)
#pragma unroll
            for (int e = 0; e < 16; e++) acc[bi][bj][e] = 0.f;

    const f16* Ablk = A + (size_t)row0 * 512;
    const f16* Bblk = Bt + (size_t)colg0 * 512;

    // stage tile t into buffer bi_: CPR gl2lds per thread (A+B)
#define STAGEG(t_, bi_)                                                        \
    {                                                                          \
        const int k0s = (t_) * BK;                                             \
        u16* Ad = smem + (bi_) * BUFE;                                         \
        u16* Bd = Ad + 128 * BK;                                               \
        _Pragma("unroll")                                                      \
        for (int i = 0; i < CPR / 2; i++) {                                    \
            int p = tid + i * 256;                                             \
            int mm = p / CPR, kc = p & (CPR - 1);                              \
            int fm = (BK == 64) ? (mm & 7) : ((mm >> 1) & 3);                  \
            int gk = ((kc ^ fm) << 3);                                         \
            gl2lds16(Ablk + (size_t)mm * 512 + k0s + gk, Ad + p * 8);          \
            gl2lds16(Bblk + (size_t)mm * 512 + k0s + gk, Bd + p * 8);          \
        }                                                                      \
    }

    STAGEG(0, 0)
    for (int t8 = 0; t8 < NT; t8++) {
        const int buf = t8 & 1;
        if (t8 < NT - 1) STAGEG(t8 + 1, buf ^ 1)   // buf^1 readers done
        if (t8 < NT - 1) {
            if constexpr (BK == 64) asm volatile("s_waitcnt vmcnt(8)" ::: "memory");
            else                    asm volatile("s_waitcnt vmcnt(4)" ::: "memory");
        } else {
            asm volatile("s_waitcnt vmcnt(0)" ::: "memory");
        }
        __builtin_amdgcn_s_barrier();              // everyone's stage(t8) landed
        __builtin_amdgcn_sched_barrier(0);
        const u16* As = smem + buf * BUFE;
        const u16* Bs = As + 128 * BK;
        __builtin_amdgcn_s_setprio(1);             // T5: favor MFMA-phase waves
#pragma unroll
        for (int t = 0; t < BK / 16; t++) {        // 32x32x16 k-steps
            f16x8 af[2], bfr[2];
#pragma unroll
            for (int bi = 0; bi < 2; bi++) {
                int r = wr * 64 + bi * 32 + nn;
                int fr = (BK == 64) ? (r & 7) : ((r >> 1) & 3);
                int ch = r * CPR + ((t * 2 + hh) ^ fr);
                af[bi] = *(const f16x8*)(As + ch * 8);
            }
#pragma unroll
            for (int bj = 0; bj < 2; bj++) {
                int n = wc * 64 + bj * 32 + nn;
                int fr = (BK == 64) ? (n & 7) : ((n >> 1) & 3);
                int ch = n * CPR + ((t * 2 + hh) ^ fr);
                bfr[bj] = *(const f16x8*)(Bs + ch * 8);
            }
#pragma unroll
            for (int bi = 0; bi < 2; bi++)
#pragma unroll
                for (int bj = 0; bj < 2; bj++)
                    acc[bi][bj] = __builtin_amdgcn_mfma_f32_32x32x16_f16(
                        af[bi], bfr[bj], acc[bi][bj], 0, 0, 0);
        }
        __builtin_amdgcn_s_setprio(0);
        __builtin_amdgcn_s_barrier();              // compute(t8) done -> buf reusable
    }
#undef STAGEG

    // C/D mapping (m74/m101): col = nn, rowoff = (reg&3) + 8*(reg>>2) + 4*hh
    if (MODE == 0) {
        const int sel = colg0 >> 9;
        const int c0 = colg0 & 511;
        if (sel < 2) {                      // Q or K: plain row-major
            f16* outp = (sel == 0) ? o0 : o1;
            const float* bp = (sel == 0) ? b0 : b1;
            const float sc = (sel == 0) ? 0.125f : 1.0f;
#pragma unroll
            for (int bj = 0; bj < 2; bj++) {
                int col = c0 + wc * 64 + bj * 32 + nn;
                float bv = bp[col];
#pragma unroll
                for (int bi = 0; bi < 2; bi++)
#pragma unroll
                    for (int rg = 0; rg < 16; rg++) {
                        int row = row0 + wr * 64 + bi * 32 +
                                  (rg & 3) + 8 * (rg >> 2) + 4 * hh;
                        outp[(size_t)row * 512 + col] =
                            (f16)(fmaxf(acc[bi][bj][rg] + bv, 0.f) * sc);
                    }
            }
        } else {                            // V: LDS transpose -> packed V^T tiles
            const int hh_head = c0 >> 6;
            f16 (*T)[136] = (f16(*)[136])smem;   // 64 x 136 fp16 (17.4KB)
            const int bb = row0 >> 11;
            const int t0 = (row0 & 2047) >> 6;
            __syncthreads();                // all waves done reading As/Bs
#pragma unroll
            for (int ph = 0; ph < 2; ph++) {
                if (wc == ph) {
#pragma unroll
                    for (int bj = 0; bj < 2; bj++) {
                        int d = bj * 32 + nn;
                        float bv = b2[c0 + ph * 64 + d];
#pragma unroll
                        for (int bi = 0; bi < 2; bi++)
#pragma unroll
                            for (int rg = 0; rg < 16; rg++) {
                                int s = wr * 64 + bi * 32 +
                                        (rg & 3) + 8 * (rg >> 2) + 4 * hh;
                                T[d][s] = (f16)fmaxf(acc[bi][bj][rg] + bv, 0.f);
                            }
                    }
                }
                __syncthreads();
#pragma unroll
                for (int ii = 0; ii < 4; ii++) {
                    int oct = tid + ii * 256;        // 1024 octets = 2 tiles
                    int tt = oct >> 9, rem = oct & 511;
                    int d = rem >> 3, s8 = rem & 7;
                    us8 val = *(const us8*)(&T[d][tt * 64 + s8 * 8]);
                    size_t dst = (((size_t)((bb * 8 + hh_head + ph) * 32 + t0 + tt)) << 12)
                                 + d * 64 + s8 * 8;
                    *(us8*)(o2v + dst) = val;
                }
                __syncthreads();
            }
        }
    } else {
#pragma unroll
        for (int bj = 0; bj < 2; bj++) {
            int col = colg0 + wc * 64 + bj * 32 + nn;
            float bv = bias_f[col];
#pragma unroll
            for (int bi = 0; bi < 2; bi++)
#pragma unroll
                for (int rg = 0; rg < 16; rg++) {
                    int row = row0 + wr * 64 + bi * 32 +
                              (rg & 3) + 8 * (rg >> 2) + 4 * hh;
                    ofp[(size_t)row * 512 + col] = fmaxf(acc[bi][bj][rg] + bv, 0.f);
                }
        }
    }
}

// ---- flash attention: 128 queries/block (8 waves share K/V tiles) ----
// R9 structure (triple-buffer, counted vmcnt, wave-skip, setprio, smap).
__global__ __launch_bounds__(512) void attn_mfma(
    const f16* __restrict__ Q, const f16* __restrict__ K,
    const u16* __restrict__ VT, const int* __restrict__ G,
    f16* __restrict__ Y, const int* __restrict__ smap) {
    __shared__ __align__(16) u16 Ks[3][4096];   // frag-image, XOR-swizzled
    __shared__ __align__(16) u16 Vs[3][4096];
    __shared__ int bnd[9];

    const int m = smap[blockIdx.x];
    const int qt = m & 15, h = (m >> 4) & 7, b = (m >> 7) & 3;
    const int q0 = qt * 128;
    const int tid = threadIdx.x;
    const int w = tid >> 6, lane = tid & 63;
    const int ln = lane & 15, quad = lane >> 4;

    const f16* Qb = Q + (size_t)b * Ssz * Dsz;
    const f16* Kb = K + (size_t)b * Ssz * Dsz;
    const u16* Vtb = VT + (size_t)(b * Hn + h) * 32 * 4096;
    const int* Gb = G + (size_t)b * Ssz;

    // group boundary table (sorted groups): bnd[g] = first i with G[i] >= g
    if (tid < 9) bnd[tid] = Ssz;
    __syncthreads();
    {
        int i0 = tid * 4;                      // 512 threads x 4 = 2048
        int4 gi = *(const int4*)(Gb + i0);
        int gp = (i0 == 0) ? -1 : Gb[i0 - 1];
        int ga[5] = {gp, gi.x, gi.y, gi.z, gi.w};
#pragma unroll
        for (int j = 0; j < 4; j++)
            for (int g = ga[j] + 1; g <= ga[j + 1]; g++) bnd[g] = i0 + j;
    }

    // Q B-frags for 16x16x32 (n=ln, k=quad*8+j), hoisted
    f16x8 qf[2];
    {
        const f16* qrow = Qb + (size_t)(q0 + w * 16 + ln) * Dsz + h * 64;
        qf[0] = *(const f16x8*)(qrow + quad * 8);
        qf[1] = *(const f16x8*)(qrow + 32 + quad * 8);
    }
    const int gq = Gb[q0 + w * 16 + ln];
    const int gqmin = Gb[q0], gqmax = Gb[q0 + 127];
    const int gwmin = Gb[q0 + w * 16];         // this wave's 16 rows
    const int gwmax = Gb[q0 + w * 16 + 15];

    // visited tile range (sorted groups => contiguous)
    int gf = 0, gl = 0; bool ov = false;
    if (lane < 32) {
        gf = Gb[lane * 64]; gl = Gb[lane * 64 + 63];
        ov = (gl >= gqmin) && (gf <= gqmax);
    }
    unsigned long long mask = __ballot(ov);
    const int kt_lo = __builtin_ctzll(mask);
    const int kt_hi = 63 - __builtin_clzll(mask);

    __syncthreads();                         // bnd ready
    const int sq = bnd[gq];
    const unsigned usz = (unsigned)(bnd[gq + 1] - sq);

    f32x4 o[4];
    const f32x4 z4 = {0.f, 0.f, 0.f, 0.f};
#pragma unroll
    for (int nd = 0; nd < 4; nd++) o[nd] = z4;
    float lsum = 0.f;

#define STAGE_K(kt, bi_)                                                       \
    {                                                                          \
        const f16* Ktile = Kb + (size_t)(kt) * 64 * Dsz + h * 64;              \
        int row = tid >> 3, c = tid & 7;                                       \
        gl2lds16(Ktile + (size_t)row * Dsz + ((c ^ (row & 7)) << 3),           \
                 Ks[bi_] + tid * 8);                                           \
    }
#define STAGE_V(kt, bi_)                                                       \
    {                                                                          \
        const u16* Vtile = Vtb + (size_t)(kt) * 4096;                          \
        int row = tid >> 3, c = tid & 7;                                       \
        gl2lds16(Vtile + row * 64 + ((c ^ (row & 7)) << 3),                    \
                 Vs[bi_] + tid * 8);                                           \
    }

    // prologue: prefetch 2 tiles
    STAGE_K(kt_lo, 0)
    STAGE_V(kt_lo, 0)
    if (kt_lo + 1 <= kt_hi) { STAGE_K(kt_lo + 1, 1) STAGE_V(kt_lo + 1, 1) }

    int buf = 0;
    for (int kt = kt_lo; kt <= kt_hi; kt++) {
        // counted wait: stage(kt) landed, stage(kt+1) stays in flight
        if (kt < kt_hi) asm volatile("s_waitcnt vmcnt(2)" ::: "memory");
        else            asm volatile("s_waitcnt vmcnt(0)" ::: "memory");
        __builtin_amdgcn_s_barrier();        // LDS(buf) ready everywhere;
        __builtin_amdgcn_sched_barrier(0);   //  buffer (buf+2)%3 reusable
        {
            int nkt = kt + 2;
            if (nkt <= kt_hi) {
                int sb = (buf >= 1) ? buf - 1 : 2;   // (buf+2)%3
                STAGE_K(nkt, sb) STAGE_V(nkt, sb)
            }
        }
        const int gkf = __shfl(gf, kt), gkl = __shfl(gl, kt);
        // per-wave skip: tile's groups vs this wave's rows' groups
        if ((gkl >= gwmin) && (gkf <= gwmax)) {
            const u16* ks = Ks[buf];
            const u16* vs = Vs[buf];
            const int k0 = kt * 64;

            f16x4 pf[4];
#pragma unroll
            for (int kb = 0; kb < 4; kb++) {
                f32x4 s = z4;
                __builtin_amdgcn_s_setprio(1);
#pragma unroll
                for (int kk = 0; kk < 2; kk++) {   // S^T = K Q^T, K=32 per mfma
                    int key = kb * 16 + ln;
                    int ch = key * 8 + ((kk * 4 + quad) ^ (key & 7));
                    f16x8 kf = *(const f16x8*)(ks + ch * 8);
                    s = __builtin_amdgcn_mfma_f32_16x16x32_f16(kf, qf[kk], s, 0, 0, 0);
                }
                __builtin_amdgcn_s_setprio(0);
                const int ckb = k0 + kb * 16 + quad * 4;
                f16x4 pp;
#pragma unroll
                for (int r = 0; r < 4; r++) {
                    float t = s[r] - 4.0f;   // Q pre-scaled; fixed-shift softmax
                    float sval = ((unsigned)(ckb + r - sq) < usz) ? t : -1e9f;
                    float e = __expf(sval);
                    lsum += e;
                    pp[r] = (f16)e;
                }
                pf[kb] = pp;
            }
            // O += P V   (P regs are already the A-operand layout for x16)
            __builtin_amdgcn_s_setprio(1);
#pragma unroll
            for (int nd = 0; nd < 4; nd++)
#pragma unroll
                for (int kc = 0; kc < 4; kc++) {
                    int addr = (((nd * 16 + ln) * 8 +
                                 ((kc * 2 + (quad >> 1)) ^ (ln & 7))) << 3) +
                               (quad & 1) * 4;
                    f16x4 vf = *(const f16x4*)(vs + addr);
                    o[nd] = __builtin_amdgcn_mfma_f32_16x16x16f16(pf[kc], vf, o[nd], 0, 0, 0);
                }
            __builtin_amdgcn_s_setprio(0);
        }
        buf = (buf == 2) ? 0 : buf + 1;
    }

    lsum += __shfl_xor(lsum, 16);
    lsum += __shfl_xor(lsum, 32);
    float linv = 1.0f / lsum;
#pragma unroll
    for (int r = 0; r < 4; r++) {
        float lr = __shfl(linv, (lane & 48) | (quad * 4 + r));
        size_t row = (size_t)b * Ssz + q0 + w * 16 + quad * 4 + r;
#pragma unroll
        for (int nd = 0; nd < 4; nd++)
            Y[row * Dsz + h * 64 + nd * 16 + ln] = (f16)(o[nd][r] * lr);
    }
#undef STAGE_K
#undef STAGE_V
}

// ============================================================================
// R14: setprio around gemm MFMA clusters (T5; role-split counted-vmcnt loop)
// + DETERMINISM PROBE for R13's unexplained absmax change (0.0078->0.0234):
// setprio cannot alter values/FP-order, so absmax must stay EXACTLY
// 0.0234375 if deterministic; any shift => BK=32 staging races => revert
// gemm0 to BK=64 next round. Predicted dur 133-135.5.
// Ledger: fills ~80, gaps ~27, kernels ~27.5 {gemm0 ~11, attn ~10.5,
// gemm1 ~3.3, prep ~1.9}. Lessons: no cross-block sync (R5/R6).
// ============================================================================
extern "C" void kernel_launch(void* const* d_in, const int* in_sizes, int n_in,
                              void* d_out, int out_size, void* d_ws, size_t ws_size,
                              hipStream_t stream) {
    const float* x  = (const float*)d_in[0];
    const int*   g  = (const int*)d_in[1];
    const float* Wq = (const float*)d_in[2];
    const float* bq = (const float*)d_in[3];
    const float* Wk = (const float*)d_in[4];
    const float* bk = (const float*)d_in[5];
    const float* Wv = (const float*)d_in[6];
    const float* bv = (const float*)d_in[7];
    const float* Wo = (const float*)d_in[8];
    const float* bo = (const float*)d_in[9];
    float* out = (float*)d_out;

    const size_t E = (size_t)Bsz * Ssz * Dsz;   // 4M elements
    f16* xb  = (f16*)d_ws;
    f16* qb  = xb + E;                  // [B,S,D] fp16 (Q pre-scaled 0.125)
    f16* kb2 = qb + E;                  // [B,S,D] fp16
    u16* vtb = (u16*)(kb2 + E);         // packed V^T [bh][t][64][64]
    f16* yb  = (f16*)(vtb + E);         // [B,S,D] fp16
    f16* Wtqkv = yb + E;                // [1536][512]
    f16* Wto   = Wtqkv + 1536 * 512;    // [512][512]
    int* smap  = (int*)(Wto + 512 * 512);   // 512-entry attn schedule map

    prep<<<2305, 256, 0, stream>>>(x, xb, Wq, Wk, Wv, Wo, Wtqkv, Wto, g, smap);
    gemm128<0, 12, 32><<<768, 256, 0, stream>>>(xb, Wtqkv, qb, kb2, vtb,
                                                bq, bk, bv, nullptr, nullptr);
    attn_mfma<<<dim3(512), 512, 0, stream>>>(qb, kb2, vtb, g, yb, smap);
    gemm128<1, 4, 64><<<256, 256, 0, stream>>>(yb, Wto, nullptr, nullptr, nullptr,
                                               nullptr, nullptr, nullptr, out, bo);
}

// Round 15
// 132.530 us; speedup vs baseline: 1.0406x; 1.0406x over previous
//
#include <hip/hip_runtime.h>
#include <cmath>

#define Bsz 4
#define Ssz 2048
#define Dsz 512
#define Hn 8

typedef unsigned short u16;
typedef _Float16 f16;
typedef __attribute__((ext_vector_type(4))) _Float16 f16x4;
typedef __attribute__((ext_vector_type(8))) _Float16 f16x8;
typedef __attribute__((ext_vector_type(8))) unsigned short us8;
typedef __attribute__((ext_vector_type(4))) float f32x4;
typedef __attribute__((ext_vector_type(16))) float f32x16;

__device__ __forceinline__ void gl2lds16(const void* g, void* l) {
    __builtin_amdgcn_global_load_lds(
        (const __attribute__((address_space(1))) void*)g,
        (__attribute__((address_space(3))) void*)l, 16, 0, 0);
}

// ---- fused prep: blocks [0,2048) convert x (fp32->fp16, 8/thread);
//      blocks [2048,2304) transpose+convert the 4 weight matrices;
//      block 2304 builds the attn schedule map (anti-correlated pairing).
__global__ __launch_bounds__(256) void prep(const float* __restrict__ x,
                                            f16* __restrict__ xb,
                                            const float* __restrict__ Wq,
                                            const float* __restrict__ Wk,
                                            const float* __restrict__ Wv,
                                            const float* __restrict__ Wo,
                                            f16* __restrict__ Wtqkv,
                                            f16* __restrict__ Wto,
                                            const int* __restrict__ gids,
                                            int* __restrict__ smap) {
    const int blk = blockIdx.x;
    const int tid = threadIdx.x;
    if (blk == 2304) {                     // schedule-map builder
        __shared__ int cntS[64];
        __shared__ int rnk[64];
        if (tid < 64) {
            int b = tid >> 4, qt = tid & 15;
            const int* Gb = gids + b * Ssz;
            int gqmin = Gb[qt * 128], gqmax = Gb[qt * 128 + 127];
            int c = 0;
            for (int kt = 0; kt < 32; kt++) {
                int gf = Gb[kt * 64], gl = Gb[kt * 64 + 63];
                c += (gl >= gqmin && gf <= gqmax) ? 1 : 0;
            }
            cntS[tid] = c;
        }
        __syncthreads();
        if (tid < 64) {
            int c = cntS[tid], r = 0;
            for (int j = 0; j < 64; j++) {
                int cj = cntS[j];
                r += ((cj > c) || (cj == c && j < tid)) ? 1 : 0;
            }
            rnk[tid] = r;
        }
        __syncthreads();
        if (tid < 64) {
            int r = rnk[tid];
            int b = tid >> 4, qt = tid & 15;
            int enc = qt | (b << 7);
#pragma unroll
            for (int h = 0; h < 8; h++) {
                int inst = r * 8 + h;
                int slot = (inst < 256) ? inst : 767 - inst;
                smap[slot] = enc | (h << 4);
            }
        }
        return;
    }
    if (blk < 2048) {
        int i = blk * 256 + tid;
        const float4* xv = (const float4*)x;
        float4 a = xv[2 * i], b = xv[2 * i + 1];
        f16x8 o;
        o[0] = (f16)a.x; o[1] = (f16)a.y; o[2] = (f16)a.z; o[3] = (f16)a.w;
        o[4] = (f16)b.x; o[5] = (f16)b.y; o[6] = (f16)b.z; o[7] = (f16)b.w;
        ((f16x8*)xb)[i] = o;
        return;
    }
    __shared__ float T[64][65];
    const int bz = blk - 2048;             // 256 blocks: 8 x 8 x 4
    const int z = bz >> 6;
    const int n0 = (bz & 7) * 64, k0 = ((bz >> 3) & 7) * 64;
    const float* W = (z == 0) ? Wq : (z == 1) ? Wk : (z == 2) ? Wv : Wo;
#pragma unroll
    for (int i = 0; i < 16; i++) {
        int e = tid + i * 256;
        int r = e >> 6, c = e & 63;
        T[r][c] = W[(size_t)(k0 + r) * Dsz + n0 + c];
    }
    __syncthreads();
    f16* dst = (z < 3) ? (Wtqkv + ((size_t)z * 512 + n0) * Dsz + k0)
                       : (Wto + (size_t)n0 * Dsz + k0);
#pragma unroll
    for (int i = 0; i < 16; i++) {
        int e = tid + i * 256;
        int r = e >> 6, c = e & 63;
        dst[(size_t)r * Dsz + c] = (f16)(T[c][r]);
    }
}

// ---- 128x128-tile fp16 MFMA GEMM (32x32x16), C = relu(A @ Bt^T + bias) ----
// R11: counted-vmcnt double-buffer (T3/T4). R12: XCD-slab swizzle (T1).
// R15: REVERT R13/R14. BK=32 was racy (determinism probe: absmax flipped
// 0.0078->0.0234->0.0078 with value-neutral setprio change => scheduling-
// dependent output; mechanism unidentified => unsafe). setprio also missed
// its timing prediction. Back to BK=64, no gemm setprio (R12 = 136.97us,
// absmax stable 0.0078125 over 13 runs).
// MODE 0: Q (x0.125) / K row-major f16; V -> packed V^T tiles. MODE 1: fp32.
template <int MODE, int NCOL>
__global__ __launch_bounds__(256) void gemm128(
    const f16* __restrict__ A, const f16* __restrict__ Bt,
    f16* o0, f16* o1, u16* o2v,
    const float* b0, const float* b1, const float* b2,
    float* ofp, const float* bias_f) {
    __shared__ __align__(16) u16 smem[2 * 2 * 128 * 64];   // 64KB: 2 x {As|Bs}
    const int tid = threadIdx.x;
    // XCD-slab swizzle: bid%8 = XCD (round-robin dispatch assumption)
    const int bid = blockIdx.x;
    const int xcd = bid & 7;
    const int idx = bid >> 3;
    const int colg0 = (idx % NCOL) * 128;
    const int row0 = (xcd * 8 + idx / NCOL) * 128;
    const int w = tid >> 6, lane = tid & 63;
    const int nn = lane & 31, hh = lane >> 5;
    const int wr = w >> 1, wc = w & 1;

    f32x16 acc[2][2];
#pragma unroll
    for (int bi = 0; bi < 2; bi++)
#pragma unroll
        for (int bj = 0; bj < 2; bj++)
#pragma unroll
            for (int e = 0; e < 16; e++) acc[bi][bj][e] = 0.f;

    const f16* Ablk = A + (size_t)row0 * 512;
    const f16* Bblk = Bt + (size_t)colg0 * 512;

    // stage tile t (k0 = t*64) into buffer bi_: 8 gl2lds per thread (A,B x4)
#define STAGEG(t_, bi_)                                                        \
    {                                                                          \
        const int k0s = (t_) * 64;                                             \
        u16* Ad = smem + (bi_) * 16384;                                        \
        u16* Bd = Ad + 8192;                                                   \
        _Pragma("unroll")                                                      \
        for (int i = 0; i < 4; i++) {                                          \
            int p = tid + i * 256;                                             \
            int mm = p >> 3, kc = p & 7;                                       \
            int gk = ((kc ^ (mm & 7)) << 3);                                   \
            gl2lds16(Ablk + (size_t)mm * 512 + k0s + gk, Ad + p * 8);          \
            gl2lds16(Bblk + (size_t)mm * 512 + k0s + gk, Bd + p * 8);          \
        }                                                                      \
    }

    STAGEG(0, 0)
    for (int t8 = 0; t8 < 8; t8++) {
        const int buf = t8 & 1;
        if (t8 < 7) STAGEG(t8 + 1, buf ^ 1)        // buf^1 readers done (end barrier t8-1)
        if (t8 < 7) asm volatile("s_waitcnt vmcnt(8)" ::: "memory");
        else        asm volatile("s_waitcnt vmcnt(0)" ::: "memory");
        __builtin_amdgcn_s_barrier();              // everyone's stage(t8) landed
        __builtin_amdgcn_sched_barrier(0);
        const u16* As = smem + buf * 16384;
        const u16* Bs = As + 8192;
#pragma unroll
        for (int t = 0; t < 4; t++) {        // four 32x32x16 k-steps
            f16x8 af[2], bfr[2];
#pragma unroll
            for (int bi = 0; bi < 2; bi++) {
                int r = wr * 64 + bi * 32 + nn;
                int ch = r * 8 + ((t * 2 + hh) ^ (r & 7));
                af[bi] = *(const f16x8*)(As + ch * 8);
            }
#pragma unroll
            for (int bj = 0; bj < 2; bj++) {
                int n = wc * 64 + bj * 32 + nn;
                int ch = n * 8 + ((t * 2 + hh) ^ (n & 7));
                bfr[bj] = *(const f16x8*)(Bs + ch * 8);
            }
#pragma unroll
            for (int bi = 0; bi < 2; bi++)
#pragma unroll
                for (int bj = 0; bj < 2; bj++)
                    acc[bi][bj] = __builtin_amdgcn_mfma_f32_32x32x16_f16(
                        af[bi], bfr[bj], acc[bi][bj], 0, 0, 0);
        }
        __builtin_amdgcn_s_barrier();              // compute(t8) done -> buf reusable
    }
#undef STAGEG

    // C/D mapping (m74/m101): col = nn, rowoff = (reg&3) + 8*(reg>>2) + 4*hh
    if (MODE == 0) {
        const int sel = colg0 >> 9;
        const int c0 = colg0 & 511;
        if (sel < 2) {                      // Q or K: plain row-major
            f16* outp = (sel == 0) ? o0 : o1;
            const float* bp = (sel == 0) ? b0 : b1;
            const float sc = (sel == 0) ? 0.125f : 1.0f;
#pragma unroll
            for (int bj = 0; bj < 2; bj++) {
                int col = c0 + wc * 64 + bj * 32 + nn;
                float bv = bp[col];
#pragma unroll
                for (int bi = 0; bi < 2; bi++)
#pragma unroll
                    for (int rg = 0; rg < 16; rg++) {
                        int row = row0 + wr * 64 + bi * 32 +
                                  (rg & 3) + 8 * (rg >> 2) + 4 * hh;
                        outp[(size_t)row * 512 + col] =
                            (f16)(fmaxf(acc[bi][bj][rg] + bv, 0.f) * sc);
                    }
            }
        } else {                            // V: LDS transpose -> packed V^T tiles
            const int hh_head = c0 >> 6;
            f16 (*T)[136] = (f16(*)[136])smem;   // 64 x 136 fp16
            const int bb = row0 >> 11;
            const int t0 = (row0 & 2047) >> 6;
            __syncthreads();                // all waves done reading As/Bs
#pragma unroll
            for (int ph = 0; ph < 2; ph++) {
                if (wc == ph) {
#pragma unroll
                    for (int bj = 0; bj < 2; bj++) {
                        int d = bj * 32 + nn;
                        float bv = b2[c0 + ph * 64 + d];
#pragma unroll
                        for (int bi = 0; bi < 2; bi++)
#pragma unroll
                            for (int rg = 0; rg < 16; rg++) {
                                int s = wr * 64 + bi * 32 +
                                        (rg & 3) + 8 * (rg >> 2) + 4 * hh;
                                T[d][s] = (f16)fmaxf(acc[bi][bj][rg] + bv, 0.f);
                            }
                    }
                }
                __syncthreads();
#pragma unroll
                for (int ii = 0; ii < 4; ii++) {
                    int oct = tid + ii * 256;        // 1024 octets = 2 tiles
                    int tt = oct >> 9, rem = oct & 511;
                    int d = rem >> 3, s8 = rem & 7;
                    us8 val = *(const us8*)(&T[d][tt * 64 + s8 * 8]);
                    size_t dst = (((size_t)((bb * 8 + hh_head + ph) * 32 + t0 + tt)) << 12)
                                 + d * 64 + s8 * 8;
                    *(us8*)(o2v + dst) = val;
                }
                __syncthreads();
            }
        }
    } else {
#pragma unroll
        for (int bj = 0; bj < 2; bj++) {
            int col = colg0 + wc * 64 + bj * 32 + nn;
            float bv = bias_f[col];
#pragma unroll
            for (int bi = 0; bi < 2; bi++)
#pragma unroll
                for (int rg = 0; rg < 16; rg++) {
                    int row = row0 + wr * 64 + bi * 32 +
                              (rg & 3) + 8 * (rg >> 2) + 4 * hh;
                    ofp[(size_t)row * 512 + col] = fmaxf(acc[bi][bj][rg] + bv, 0.f);
                }
        }
    }
}

// ---- flash attention: 128 queries/block (8 waves share K/V tiles) ----
// R9 structure (triple-buffer, counted vmcnt, wave-skip, setprio, smap).
__global__ __launch_bounds__(512) void attn_mfma(
    const f16* __restrict__ Q, const f16* __restrict__ K,
    const u16* __restrict__ VT, const int* __restrict__ G,
    f16* __restrict__ Y, const int* __restrict__ smap) {
    __shared__ __align__(16) u16 Ks[3][4096];   // frag-image, XOR-swizzled
    __shared__ __align__(16) u16 Vs[3][4096];
    __shared__ int bnd[9];

    const int m = smap[blockIdx.x];
    const int qt = m & 15, h = (m >> 4) & 7, b = (m >> 7) & 3;
    const int q0 = qt * 128;
    const int tid = threadIdx.x;
    const int w = tid >> 6, lane = tid & 63;
    const int ln = lane & 15, quad = lane >> 4;

    const f16* Qb = Q + (size_t)b * Ssz * Dsz;
    const f16* Kb = K + (size_t)b * Ssz * Dsz;
    const u16* Vtb = VT + (size_t)(b * Hn + h) * 32 * 4096;
    const int* Gb = G + (size_t)b * Ssz;

    // group boundary table (sorted groups): bnd[g] = first i with G[i] >= g
    if (tid < 9) bnd[tid] = Ssz;
    __syncthreads();
    {
        int i0 = tid * 4;                      // 512 threads x 4 = 2048
        int4 gi = *(const int4*)(Gb + i0);
        int gp = (i0 == 0) ? -1 : Gb[i0 - 1];
        int ga[5] = {gp, gi.x, gi.y, gi.z, gi.w};
#pragma unroll
        for (int j = 0; j < 4; j++)
            for (int g = ga[j] + 1; g <= ga[j + 1]; g++) bnd[g] = i0 + j;
    }

    // Q B-frags for 16x16x32 (n=ln, k=quad*8+j), hoisted
    f16x8 qf[2];
    {
        const f16* qrow = Qb + (size_t)(q0 + w * 16 + ln) * Dsz + h * 64;
        qf[0] = *(const f16x8*)(qrow + quad * 8);
        qf[1] = *(const f16x8*)(qrow + 32 + quad * 8);
    }
    const int gq = Gb[q0 + w * 16 + ln];
    const int gqmin = Gb[q0], gqmax = Gb[q0 + 127];
    const int gwmin = Gb[q0 + w * 16];         // this wave's 16 rows
    const int gwmax = Gb[q0 + w * 16 + 15];

    // visited tile range (sorted groups => contiguous)
    int gf = 0, gl = 0; bool ov = false;
    if (lane < 32) {
        gf = Gb[lane * 64]; gl = Gb[lane * 64 + 63];
        ov = (gl >= gqmin) && (gf <= gqmax);
    }
    unsigned long long mask = __ballot(ov);
    const int kt_lo = __builtin_ctzll(mask);
    const int kt_hi = 63 - __builtin_clzll(mask);

    __syncthreads();                         // bnd ready
    const int sq = bnd[gq];
    const unsigned usz = (unsigned)(bnd[gq + 1] - sq);

    f32x4 o[4];
    const f32x4 z4 = {0.f, 0.f, 0.f, 0.f};
#pragma unroll
    for (int nd = 0; nd < 4; nd++) o[nd] = z4;
    float lsum = 0.f;

#define STAGE_K(kt, bi_)                                                       \
    {                                                                          \
        const f16* Ktile = Kb + (size_t)(kt) * 64 * Dsz + h * 64;              \
        int row = tid >> 3, c = tid & 7;                                       \
        gl2lds16(Ktile + (size_t)row * Dsz + ((c ^ (row & 7)) << 3),           \
                 Ks[bi_] + tid * 8);                                           \
    }
#define STAGE_V(kt, bi_)                                                       \
    {                                                                          \
        const u16* Vtile = Vtb + (size_t)(kt) * 4096;                          \
        int row = tid >> 3, c = tid & 7;                                       \
        gl2lds16(Vtile + row * 64 + ((c ^ (row & 7)) << 3),                    \
                 Vs[bi_] + tid * 8);                                           \
    }

    // prologue: prefetch 2 tiles
    STAGE_K(kt_lo, 0)
    STAGE_V(kt_lo, 0)
    if (kt_lo + 1 <= kt_hi) { STAGE_K(kt_lo + 1, 1) STAGE_V(kt_lo + 1, 1) }

    int buf = 0;
    for (int kt = kt_lo; kt <= kt_hi; kt++) {
        // counted wait: stage(kt) landed, stage(kt+1) stays in flight
        if (kt < kt_hi) asm volatile("s_waitcnt vmcnt(2)" ::: "memory");
        else            asm volatile("s_waitcnt vmcnt(0)" ::: "memory");
        __builtin_amdgcn_s_barrier();        // LDS(buf) ready everywhere;
        __builtin_amdgcn_sched_barrier(0);   //  buffer (buf+2)%3 reusable
        {
            int nkt = kt + 2;
            if (nkt <= kt_hi) {
                int sb = (buf >= 1) ? buf - 1 : 2;   // (buf+2)%3
                STAGE_K(nkt, sb) STAGE_V(nkt, sb)
            }
        }
        const int gkf = __shfl(gf, kt), gkl = __shfl(gl, kt);
        // per-wave skip: tile's groups vs this wave's rows' groups
        if ((gkl >= gwmin) && (gkf <= gwmax)) {
            const u16* ks = Ks[buf];
            const u16* vs = Vs[buf];
            const int k0 = kt * 64;

            f16x4 pf[4];
#pragma unroll
            for (int kb = 0; kb < 4; kb++) {
                f32x4 s = z4;
                __builtin_amdgcn_s_setprio(1);
#pragma unroll
                for (int kk = 0; kk < 2; kk++) {   // S^T = K Q^T, K=32 per mfma
                    int key = kb * 16 + ln;
                    int ch = key * 8 + ((kk * 4 + quad) ^ (key & 7));
                    f16x8 kf = *(const f16x8*)(ks + ch * 8);
                    s = __builtin_amdgcn_mfma_f32_16x16x32_f16(kf, qf[kk], s, 0, 0, 0);
                }
                __builtin_amdgcn_s_setprio(0);
                const int ckb = k0 + kb * 16 + quad * 4;
                f16x4 pp;
#pragma unroll
                for (int r = 0; r < 4; r++) {
                    float t = s[r] - 4.0f;   // Q pre-scaled; fixed-shift softmax
                    float sval = ((unsigned)(ckb + r - sq) < usz) ? t : -1e9f;
                    float e = __expf(sval);
                    lsum += e;
                    pp[r] = (f16)e;
                }
                pf[kb] = pp;
            }
            // O += P V   (P regs are already the A-operand layout for x16)
            __builtin_amdgcn_s_setprio(1);
#pragma unroll
            for (int nd = 0; nd < 4; nd++)
#pragma unroll
                for (int kc = 0; kc < 4; kc++) {
                    int addr = (((nd * 16 + ln) * 8 +
                                 ((kc * 2 + (quad >> 1)) ^ (ln & 7))) << 3) +
                               (quad & 1) * 4;
                    f16x4 vf = *(const f16x4*)(vs + addr);
                    o[nd] = __builtin_amdgcn_mfma_f32_16x16x16f16(pf[kc], vf, o[nd], 0, 0, 0);
                }
            __builtin_amdgcn_s_setprio(0);
        }
        buf = (buf == 2) ? 0 : buf + 1;
    }

    lsum += __shfl_xor(lsum, 16);
    lsum += __shfl_xor(lsum, 32);
    float linv = 1.0f / lsum;
#pragma unroll
    for (int r = 0; r < 4; r++) {
        float lr = __shfl(linv, (lane & 48) | (quad * 4 + r));
        size_t row = (size_t)b * Ssz + q0 + w * 16 + quad * 4 + r;
#pragma unroll
        for (int nd = 0; nd < 4; nd++)
            Y[row * Dsz + h * 64 + nd * 16 + ln] = (f16)(o[nd][r] * lr);
    }
#undef STAGE_K
#undef STAGE_V
}

// ============================================================================
// R15: REVERT to R12 config (last known-good: 136.97us, absmax 0.0078125
// stable over 13 runs). R13's BK=32 proved RACY via the R14 determinism
// probe (absmax flipped with a value-neutral setprio change => output is
// scheduling-dependent); R14's gemm setprio also missed its prediction.
// Predicted: dur 135.5-138.5, absmax EXACTLY 0.0078125.
// Ledger at this config: fills ~80 (harness-fixed), gaps ~27 (4 nodes;
// cross-block sync banned per R5/R6), kernels ~29 {gemm0 ~13.5 (L2/MFMA
// floor ~7), attn ~11, gemm1 ~3.3, prep ~1.9}. Remaining levers are banned,
// proven-null, or proven-racy => expect ROOFLINE declaration next round.
// ============================================================================
extern "C" void kernel_launch(void* const* d_in, const int* in_sizes, int n_in,
                              void* d_out, int out_size, void* d_ws, size_t ws_size,
                              hipStream_t stream) {
    const float* x  = (const float*)d_in[0];
    const int*   g  = (const int*)d_in[1];
    const float* Wq = (const float*)d_in[2];
    const float* bq = (const float*)d_in[3];
    const float* Wk = (const float*)d_in[4];
    const float* bk = (const float*)d_in[5];
    const float* Wv = (const float*)d_in[6];
    const float* bv = (const float*)d_in[7];
    const float* Wo = (const float*)d_in[8];
    const float* bo = (const float*)d_in[9];
    float* out = (float*)d_out;

    const size_t E = (size_t)Bsz * Ssz * Dsz;   // 4M elements
    f16* xb  = (f16*)d_ws;
    f16* qb  = xb + E;                  // [B,S,D] fp16 (Q pre-scaled 0.125)
    f16* kb2 = qb + E;                  // [B,S,D] fp16
    u16* vtb = (u16*)(kb2 + E);         // packed V^T [bh][t][64][64]
    f16* yb  = (f16*)(vtb + E);         // [B,S,D] fp16
    f16* Wtqkv = yb + E;                // [1536][512]
    f16* Wto   = Wtqkv + 1536 * 512;    // [512][512]
    int* smap  = (int*)(Wto + 512 * 512);   // 512-entry attn schedule map

    prep<<<2305, 256, 0, stream>>>(x, xb, Wq, Wk, Wv, Wo, Wtqkv, Wto, g, smap);
    gemm128<0, 12><<<768, 256, 0, stream>>>(xb, Wtqkv, qb, kb2, vtb,
                                            bq, bk, bv, nullptr, nullptr);
    attn_mfma<<<dim3(512), 512, 0, stream>>>(qb, kb2, vtb, g, yb, smap);
    gemm128<1, 4><<<256, 256, 0, stream>>>(yb, Wto, nullptr, nullptr, nullptr,
                                           nullptr, nullptr, nullptr, out, bo);
}